// Round 19
// baseline (118.789 us; speedup 1.0000x reference)
//
#include <hip/hip_runtime.h>

#define N_ATOMS 262144
#define NGRAPH  2048
#define INV_SCALE 0.17677669529663687f  // 1/sqrt(32)

typedef float f32x2 __attribute__((ext_vector_type(2)));
typedef float f32x4 __attribute__((ext_vector_type(4)));

// CDNA packed fp32 (VOP3P), R5-verified.
__device__ __forceinline__ f32x2 pk_mul(f32x2 a, f32x2 b) {
  f32x2 d; asm("v_pk_mul_f32 %0, %1, %2" : "=v"(d) : "v"(a), "v"(b)); return d;
}
__device__ __forceinline__ f32x2 pk_fma(f32x2 a, f32x2 b, f32x2 c) {
  f32x2 d; asm("v_pk_fma_f32 %0, %1, %2, %3" : "=v"(d) : "v"(a), "v"(b), "v"(c)); return d;
}
__device__ __forceinline__ f32x2 pk_fma_blo(f32x2 a, f32x2 b, f32x2 c) {
  f32x2 d; asm("v_pk_fma_f32 %0, %1, %2, %3 op_sel_hi:[0,1,1]"
               : "=v"(d) : "v"(a), "v"(b), "v"(c)); return d;
}
__device__ __forceinline__ f32x2 pk_fma_bhi(f32x2 a, f32x2 b, f32x2 c) {
  f32x2 d; asm("v_pk_fma_f32 %0, %1, %2, %3 op_sel:[1,0,0]"
               : "=v"(d) : "v"(a), "v"(b), "v"(c)); return d;
}

// ---------------- K1: fused prep (blocks 0-7) + bounds (blocks 8-15).
__global__ void k_pre(const float* __restrict__ Wk, const float* __restrict__ bk,
                      const float* __restrict__ q, const int* __restrict__ batch,
                      float* __restrict__ P, float* __restrict__ c,
                      int* __restrict__ bounds) {
  if (blockIdx.x < 8) {
    int h = blockIdx.x, i = threadIdx.x;
    float s = 0.f;
    #pragma unroll
    for (int d = 0; d < 32; ++d)
      s = fmaf(Wk[i * 256 + h * 32 + d], q[h * 32 + d], s);
    P[h * 256 + i] = s;
    if (i == 0) {
      float cc = 0.f;
      #pragma unroll
      for (int d = 0; d < 32; ++d) cc = fmaf(bk[h * 32 + d], q[h * 32 + d], cc);
      c[h] = cc;
    }
  } else {
    int g = (blockIdx.x - 8) * 256 + threadIdx.x;
    if (g >= NGRAPH) return;
    int lo = 0, hi = N_ATOMS;
    while (lo < hi) {
      int mid = (lo + hi) >> 1;
      if (batch[mid] < g) lo = mid + 1; else hi = mid;
    }
    bounds[2 * g] = lo;
    if (g > 0) bounds[2 * g - 1] = lo;
    if (g == NGRAPH - 1) bounds[2 * g + 1] = N_ATOMS;
  }
}

// fold4: 4 head-partials/lane over 64 lanes -> full dot of local head hl at
// every lane, hl = 2*bit4 + bit5 of lane (level lane&16 carries weight 2,
// level lane&32 weight 1 — same selection idiom as the R2-verified fold8).
__device__ __forceinline__ float fold4(float acc[4], int lane) {
  {
    int m = lane & 16;
    float nw[2];
    #pragma unroll
    for (int j = 0; j < 2; ++j) {
      float snd = m ? acc[j] : acc[j + 2];
      float rcv = __shfl_xor(snd, 16, 64);
      nw[j] = (m ? acc[j + 2] : acc[j]) + rcv;
    }
    acc[0] = nw[0]; acc[1] = nw[1];
  }
  float r;
  {
    int m = lane & 32;
    float snd = m ? acc[0] : acc[1];
    float rcv = __shfl_xor(snd, 32, 64);
    r = (m ? acc[1] : acc[0]) + rcv;
  }
  r += __shfl_xor(r, 1, 64);
  r += __shfl_xor(r, 2, 64);
  r += __shfl_xor(r, 4, 64);
  r += __shfl_xor(r, 8, 64);
  return r;
}

// ---------------- K2: fused scores + exp + weighted accumulate.
// HEAD-SPLIT: 8 waves/block; wave wv -> heads (wv&1)*4..+3, atom stream
// ar = wv>>1 (stride 4). Per-wave state halves (Pl2=16, A2=16 VGPRs) ->
// VGPR<=64 -> 8 waves/SIMD (32/CU). Wave pairs read the same x rows
// (second is L1-hit; plain loads, no NT). R18 bug fixed: hl = 2*bit4+bit5
// = ((lane>>3)&2)|((lane>>5)&1)  [R18 had ((lane>>4)&2): double-counted b5].
__global__ __launch_bounds__(512, 8) void k_fused(const float* __restrict__ x,
                                                  const float* __restrict__ P,
                                                  const float* __restrict__ c,
                                                  const int* __restrict__ bounds,
                                                  float* __restrict__ Ag) {
  int b = blockIdx.x;
  int s = bounds[2 * b], e = bounds[2 * b + 1];
  int t = threadIdx.x, lane = t & 63, wv = t >> 6;  // 8 waves
  int hh = wv & 1, ar = wv >> 1;
  int hl = ((lane >> 3) & 2) | ((lane >> 5) & 1);   // local head 0..3 (FIXED)

  f32x2 Pl2[4][2];
  #pragma unroll
  for (int k = 0; k < 4; ++k) {
    f32x4 pv = *reinterpret_cast<const f32x4*>(P + (hh * 4 + k) * 256 + 4 * lane);
    Pl2[k][0] = __builtin_shufflevector(pv, pv, 0, 1);
    Pl2[k][1] = __builtin_shufflevector(pv, pv, 2, 3);
  }
  float cl = c[hh * 4 + hl];

  f32x2 A2[4][2];
  #pragma unroll
  for (int k = 0; k < 4; ++k) { A2[k][0] = (f32x2)0.f; A2[k][1] = (f32x2)0.f; }
  float dacc = 0.f;

  __shared__ float elds[8][4];   // per-wave e-table (4 heads)
  __shared__ float Asc[8][256];  // 8 KB chunked epilogue buffer
  __shared__ float dws[8][4];
  __shared__ float dinvs[8];

  for (int n = s + ar; n < e; n += 4) {
    f32x4 xq = *reinterpret_cast<const f32x4*>(x + (size_t)n * 256 + 4 * lane);
    f32x2 xlo = __builtin_shufflevector(xq, xq, 0, 1);
    f32x2 xhi = __builtin_shufflevector(xq, xq, 2, 3);

    float acc[4];
    #pragma unroll
    for (int k = 0; k < 4; ++k) {
      f32x2 p = pk_fma(xhi, Pl2[k][1], pk_mul(xlo, Pl2[k][0]));
      acc[k] = p[0] + p[1];
    }
    float r = fold4(acc, lane);
    float ev = __expf((r + cl) * INV_SCALE);
    dacc += ev;

    if ((lane & 15) == 0) elds[wv][hl] = ev;  // lanes 0,32,16,48 -> hl 0,1,2,3
    f32x4 e4 = *reinterpret_cast<const f32x4*>(&elds[wv][0]);
    f32x2 ep0 = __builtin_shufflevector(e4, e4, 0, 1);
    f32x2 ep1 = __builtin_shufflevector(e4, e4, 2, 3);
    A2[0][0] = pk_fma_blo(ep0, xlo, A2[0][0]);
    A2[0][1] = pk_fma_blo(ep0, xhi, A2[0][1]);
    A2[1][0] = pk_fma_bhi(ep0, xlo, A2[1][0]);
    A2[1][1] = pk_fma_bhi(ep0, xhi, A2[1][1]);
    A2[2][0] = pk_fma_blo(ep1, xlo, A2[2][0]);
    A2[2][1] = pk_fma_blo(ep1, xhi, A2[2][1]);
    A2[3][0] = pk_fma_bhi(ep1, xlo, A2[3][0]);
    A2[3][1] = pk_fma_bhi(ep1, xhi, A2[3][1]);
  }

  // ---- epilogue: denominators, then 4 passes (one local head each).
  if ((lane & 15) == 0) dws[wv][hl] = dacc;
  __syncthreads();
  if (t < 8) {
    int hhg = t >> 2, hlg = t & 3;
    float ds = dws[hhg][hlg] + dws[hhg + 2][hlg] +
               dws[hhg + 4][hlg] + dws[hhg + 6][hlg];
    dinvs[t] = ds > 0.f ? 1.0f / ds : 0.f;
  }
  __syncthreads();
  int col = t & 255, which = t >> 8;  // which = head-half
  #pragma unroll
  for (int p = 0; p < 4; ++p) {
    float4 av;
    av.x = A2[p][0][0]; av.y = A2[p][0][1];
    av.z = A2[p][1][0]; av.w = A2[p][1][1];
    *reinterpret_cast<float4*>(&Asc[wv][4 * lane]) = av;
    __syncthreads();
    float v = Asc[which][col] + Asc[which + 2][col] +
              Asc[which + 4][col] + Asc[which + 6][col];
    int g = which * 4 + p;
    Ag[(size_t)b * 2048 + (size_t)g * 256 + col] = v * dinvs[g];
    __syncthreads();
  }
}

// ---------------- K5: att = A . Wv + bv (nonempty), out = att . Wo + bo
__global__ __launch_bounds__(256) void k_out(const float* __restrict__ Ag,
                                             const int* __restrict__ bounds,
                                             const float* __restrict__ Wv,
                                             const float* __restrict__ bv,
                                             const float* __restrict__ Wo,
                                             const float* __restrict__ bo,
                                             float* __restrict__ out) {
  __shared__ float Alds[4 * 2048];   // 32 KB
  __shared__ float attlds[4 * 256];  // 4 KB
  __shared__ float eflag[4];
  int b0 = blockIdx.x * 4;
  int t = threadIdx.x;
  #pragma unroll
  for (int r = 0; r < 32; ++r) {
    int idx = r * 256 + t;
    Alds[idx] = Ag[(size_t)b0 * 2048 + idx];
  }
  if (t < 4) {
    int s = bounds[2 * (b0 + t)], e = bounds[2 * (b0 + t) + 1];
    eflag[t] = (e > s) ? 1.0f : 0.0f;
  }
  __syncthreads();
  int h = t >> 5;
  float bvk = bv[t];
  float acc[4];
  #pragma unroll
  for (int g = 0; g < 4; ++g) acc[g] = 0.f;
  for (int i4 = 0; i4 < 64; ++i4) {
    float aa[4][4];
    #pragma unroll
    for (int g = 0; g < 4; ++g) {
      float4 v = *reinterpret_cast<const float4*>(&Alds[g * 2048 + h * 256 + i4 * 4]);
      aa[g][0] = v.x; aa[g][1] = v.y; aa[g][2] = v.z; aa[g][3] = v.w;
    }
    #pragma unroll
    for (int j = 0; j < 4; ++j) {
      float wvv = Wv[(size_t)(i4 * 4 + j) * 256 + t];
      #pragma unroll
      for (int g = 0; g < 4; ++g) acc[g] = fmaf(aa[g][j], wvv, acc[g]);
    }
  }
  #pragma unroll
  for (int g = 0; g < 4; ++g) attlds[g * 256 + t] = acc[g] + bvk * eflag[g];
  __syncthreads();
  float boj = bo[t];
  float o[4];
  #pragma unroll
  for (int g = 0; g < 4; ++g) o[g] = boj;
  for (int k4 = 0; k4 < 64; ++k4) {
    float aa[4][4];
    #pragma unroll
    for (int g = 0; g < 4; ++g) {
      float4 v = *reinterpret_cast<const float4*>(&attlds[g * 256 + k4 * 4]);
      aa[g][0] = v.x; aa[g][1] = v.y; aa[g][2] = v.z; aa[g][3] = v.w;
    }
    #pragma unroll
    for (int j = 0; j < 4; ++j) {
      float wo = Wo[(size_t)(k4 * 4 + j) * 256 + t];
      #pragma unroll
      for (int g = 0; g < 4; ++g) o[g] = fmaf(aa[g][j], wo, o[g]);
    }
  }
  #pragma unroll
  for (int g = 0; g < 4; ++g) out[(size_t)(b0 + g) * 256 + t] = o[g];
}

extern "C" void kernel_launch(void* const* d_in, const int* in_sizes, int n_in,
                              void* d_out, int out_size, void* d_ws, size_t ws_size,
                              hipStream_t stream) {
  const float* x   = (const float*)d_in[0];
  const int*   bat = (const int*)d_in[1];
  const float* q   = (const float*)d_in[2];
  const float* Wk  = (const float*)d_in[3];
  const float* bk  = (const float*)d_in[4];
  const float* Wv  = (const float*)d_in[5];
  const float* bv  = (const float*)d_in[6];
  const float* Wo  = (const float*)d_in[7];
  const float* bo  = (const float*)d_in[8];
  float* out = (float*)d_out;

  float* ws = (float*)d_ws;
  float* P      = ws;                 // 2048 floats
  float* c      = ws + 2048;          // 8 floats
  int*   bounds = (int*)(ws + 4096);  // 4096 ints
  float* Ag     = ws + 8192;          // 2048*2048 floats

  k_pre<<<16, 256, 0, stream>>>(Wk, bk, q, bat, P, c, bounds);
  k_fused<<<NGRAPH, 512, 0, stream>>>(x, P, c, bounds, Ag);
  k_out<<<NGRAPH / 4, 256, 0, stream>>>(Ag, bounds, Wv, bv, Wo, bo, out);
}